// Round 4
// baseline (847.736 us; speedup 1.0000x reference)
//
#include <hip/hip_runtime.h>

#define N_NODES 50000
#define N_EDGES 800000
#define D 128
#define NB 782                 // buckets: bucket = dst >> 6, 64 nodes = 1 gmm block
#define CAPB 1280              // slots per bucket (mean 1023, +8 sigma)
#define CAP 8                  // LDS staging slots per bucket in partition role
#define P1B 256                // partition blocks in k_a
#define EPB ((N_EDGES + P1B - 1) / P1B)  // 3125 edges/block
#define WPB 16                 // weight-pack blocks
#define XC0 (P1B + WPB + 1)    // first xcast block = 273
#define KA_BLOCKS (XC0 + (N_NODES * 16) / 256)  // 273 + 3125 = 3398

typedef __attribute__((ext_vector_type(8))) short short8;
typedef __attribute__((ext_vector_type(4))) float f32x4;

// round-to-nearest-even f32 -> bf16 (as ushort)
__device__ __forceinline__ unsigned short f2bf(float f) {
    unsigned int u = __builtin_bit_cast(unsigned int, f);
    u += 0x7FFFu + ((u >> 16) & 1u);
    return (unsigned short)(u >> 16);
}
__device__ __forceinline__ float bf2f(unsigned short h) {
    unsigned int u = ((unsigned int)h) << 16;
    return __builtin_bit_cast(float, u);
}

// ---------------------------------------------------------------------------
// zero per-bucket fill counters
__global__ void k_init(int* __restrict__ gcur) {
    const int t = threadIdx.x;
    if (t < NB) gcur[t] = 0;
}

// ---------------------------------------------------------------------------
// Fused independent front-end (31 KB LDS -> 5 blocks/CU for every role):
//   blocks [0,256): edge partition into 782 fixed-base buckets (LDS staging)
//   blocks [256,272): pack Wab = [Wc + Wc@Wt ; W0 - Wt] into bf16 B-fragments
//   block 272: bv = bc + bc@Wt
//   blocks [273,...): xb[n] = bf16(x[n])
__global__ __launch_bounds__(256) void k_a(const int* __restrict__ src,
                                           const int* __restrict__ dst,
                                           int* __restrict__ gcur,
                                           unsigned int* __restrict__ pbuf,
                                           const float* __restrict__ Wc,
                                           const float* __restrict__ W0,
                                           const float* __restrict__ Wt,
                                           const float* __restrict__ bc,
                                           const float* __restrict__ x,
                                           unsigned short* __restrict__ Wp,
                                           float* __restrict__ bv,
                                           unsigned short* __restrict__ xb) {
    __shared__ unsigned int stage[NB][CAP + 1];  // 28.2 KB (+1: drain conflict-free)
    __shared__ int scnt[NB];                     // 3.1 KB
    const int t = threadIdx.x;
    const unsigned int bid = blockIdx.x;

    if (bid < P1B) {  // ---- edge partition role ----
        for (int i = t; i < NB; i += 256) scnt[i] = 0;
        __syncthreads();

        const long e0 = (long)bid * EPB;
        const long e1 = (e0 + EPB < N_EDGES) ? e0 + EPB : N_EDGES;
        for (long e = e0 + t; e < e1; e += 256) {
            const int s = src[e];
            const int d = dst[e];
            const int b = d >> 6;
            const unsigned int p = ((unsigned int)(d & 63) << 16) | (unsigned int)s;
            const int slot = atomicAdd(&scnt[b], 1);
            if (slot < CAP) {
                stage[b][slot] = p;
            } else {  // spill (~0.8% of edges at CAP=8; correct for any dist)
                const int pos = atomicAdd(&gcur[b], 1);
                if (pos < CAPB) pbuf[(long)b * CAPB + pos] = p;
            }
        }
        __syncthreads();
        for (int bb = t; bb < NB; bb += 256) {
            const int n = (scnt[bb] < CAP) ? scnt[bb] : CAP;
            if (n > 0) {
                const int pos = atomicAdd(&gcur[bb], n);
                for (int i = 0; i < n; ++i)
                    if (pos + i < CAPB) pbuf[(long)bb * CAPB + pos + i] = stage[bb][i];
            }
        }
        return;
    }

    if (bid < P1B + WPB) {  // ---- weight pack role (L2-resident inputs) ----
        const int id = (int)(bid - P1B) * 256 + t;  // 0..4095
        const int lane = id & 63;
        const int tile = (id >> 6) & 7;
        const int step = id >> 9;
        const int n = tile * 16 + (lane & 15);
        const int kbase = step * 32 + (lane >> 4) * 8;
        float f[8];
#pragma unroll
        for (int j = 0; j < 8; ++j) {
            const int k = kbase + j;
            f[j] = (k < D) ? Wc[k * D + n]
                           : (W0[(k - D) * D + n] - Wt[(k - D) * D + n]);
        }
        if (kbase < D) {  // uniform per wave
#pragma unroll 8
            for (int m = 0; m < D; ++m) {
                const float wt = Wt[m * D + n];
#pragma unroll
                for (int j = 0; j < 8; ++j) f[j] += Wc[(kbase + j) * D + m] * wt;
            }
        }
        unsigned short v[8];
#pragma unroll
        for (int j = 0; j < 8; ++j) v[j] = f2bf(f[j]);
        *(uint4*)(Wp + (long)id * 8) = *(uint4*)v;
        return;
    }

    if (bid == P1B + WPB) {  // ---- bias role ----
        if (t < D) {
            float acc = bc[t];
#pragma unroll 16
            for (int k = 0; k < D; ++k) acc += bc[k] * Wt[k * D + t];
            bv[t] = acc;
        }
        return;
    }

    // ---- xcast role: xb = bf16(x) ----
    const int gid = (int)(bid - XC0) * 256 + t;  // 0 .. N*16-1
    const int node = gid >> 4;
    const int c = gid & 15;
    const float4 a = ((const float4*)x)[(long)node * 32 + c * 2];
    const float4 b = ((const float4*)x)[(long)node * 32 + c * 2 + 1];
    const float f[8] = {a.x, a.y, a.z, a.w, b.x, b.y, b.z, b.w};
    unsigned short vb[8];
#pragma unroll
    for (int j = 0; j < 8; ++j) vb[j] = f2bf(f[j]);
    *(uint4*)(xb + (long)node * 128 + c * 8) = *(uint4*)vb;
}

// ---------------------------------------------------------------------------
// Per-bucket degree count: 64-counter LDS hist over the bucket list -> dinv.
__global__ __launch_bounds__(256) void k_deg(const unsigned int* __restrict__ pbuf,
                                             const int* __restrict__ gcur,
                                             float* __restrict__ dinv) {
    __shared__ int h[64];
    const int b = blockIdx.x;
    const int t = threadIdx.x;
    if (t < 64) h[t] = 0;
    __syncthreads();
    int n = gcur[b];
    if (n > CAPB) n = CAPB;
    const long base = (long)b * CAPB;
    for (int i = t; i < n; i += 256) atomicAdd(&h[pbuf[base + i] >> 16], 1);
    __syncthreads();
    if (t < 64) {
        const int node = b * 64 + t;
        if (node < N_NODES) dinv[node] = rsqrtf((float)h[t] + 1.0f);
    }
}

// ---------------------------------------------------------------------------
// Fused gather + GEMM, LDS-accumulate version. Block = 64 rows = 1 bucket,
// 512 threads = 8 waves.
// Phase 1: stream the (unordered) bucket edge list; each edge adds
//          dinv[src]*x[src] into its dst row of a f32 LDS tile (ds_add_f32).
//          Self-loops = 64 synthetic edges (src=node, weight dinv[node]).
//          Tile layout: row stride 129 f32, element f=8c+j stored at p=16j+c
//          -> ~2-way bank spread on the 16-lane chunked ds_adds.
// Phase 2: scale rows by dinv[dst], convert to bf16 XOR-swizzled tile.
// Phase 3: wave (wr,wc): rows wr*16..+15, cols wc*64..+63 of
//          [64x256] @ Wab[256x128]: k 0..127 from tile, k 128..255 from xb.
__global__ __launch_bounds__(512) void k_gmm(const unsigned short* __restrict__ xb,
                                             const float* __restrict__ dinv,
                                             const unsigned int* __restrict__ pbuf,
                                             const int* __restrict__ gcur,
                                             const unsigned short* __restrict__ Wp,
                                             const float* __restrict__ bv,
                                             float* __restrict__ out) {
    __shared__ float ft[64 * 129];     // 33 KB f32 accumulation tile
    __shared__ unsigned int ov[4096];  // 16 KB: elist (ph1) / bf16 tile (ph2+)
    const int tid = threadIdx.x;
    const int wave = tid >> 6;  // 0..7
    const int lane = tid & 63;
    const int c = lane & 15;    // 8-elem chunk
    const int s = lane >> 4;    // edge slot
    const int b = blockIdx.x;
    const int row0 = b * 64;
    int n = gcur[b];
    if (n > CAPB) n = CAPB;

    // phase 0: zero tile + stage edge list
    for (int i = tid; i < 64 * 129; i += 512) ft[i] = 0.0f;
    unsigned int* elist = ov;
    for (int i = tid; i < n; i += 512) elist[i] = pbuf[(long)b * CAPB + i];
    __syncthreads();

    // phase 1: accumulate
    const int m = 64 + n;            // synthetic self edges first
    const int mp = (m + 63) & ~63;   // pad to 64 (8 waves x 8 edges)
    for (int base = wave * 8; base < mp; base += 64) {
        float dg[2];
        short8 vg[2];
        int dl[2];
#pragma unroll
        for (int g = 0; g < 2; ++g) {
            const int idx = base + g * 4 + s;
            int sg, dj;
            float w = 1.0f;
            if (idx < 64) {  // self edge: weight dinv[node]
                dj = idx;
                sg = row0 + idx;
                if (sg >= N_NODES) sg = N_NODES - 1;  // dead row, clamped load
            } else if (idx < m) {
                const unsigned int p = elist[idx - 64];
                sg = (int)(p & 0xFFFFu);
                dj = (int)(p >> 16);
            } else {  // padding
                sg = 0;
                dj = 0;
                w = 0.0f;
            }
            dg[g] = w * dinv[sg];
            vg[g] = *(const short8*)(xb + (long)sg * 128 + c * 8);
            dl[g] = dj;
        }
#pragma unroll
        for (int g = 0; g < 2; ++g) {
            const int ab = dl[g] * 129 + c;
            const float d = dg[g];
#pragma unroll
            for (int j = 0; j < 8; ++j)
                atomicAdd(&ft[ab + 16 * j], d * bf2f((unsigned short)vg[g][j]));
        }
    }
    __syncthreads();

    // phase 2: scale by dinv[dst], convert to bf16 swizzled tile
    unsigned short* bt = (unsigned short*)ov;
#pragma unroll
    for (int rr = 0; rr < 2; ++rr) {
        const int r = wave * 8 + s * 2 + rr;
        const int node = row0 + r;
        const float di = (node < N_NODES) ? dinv[node] : 0.0f;
        unsigned short o[8];
#pragma unroll
        for (int j = 0; j < 8; ++j)
            o[j] = f2bf(di * ft[r * 129 + 16 * j + c]);  // logical elem 8c+j
        *(uint4*)((char*)bt + r * 256 + ((c * 16) ^ ((r & 7) << 4))) = *(uint4*)o;
    }
    __syncthreads();

    // phase 3: GEMM. wave (wr,wc) -> rows wr*16..+15, cols wc*64..+63
    const int lr = lane & 15;
    const int quad = lane >> 4;
    const int wr = wave & 3;
    const int wc = wave >> 2;
    const int rloc = wr * 16 + lr;  // tile row this lane reads
    int ar = row0 + rloc;
    if (ar >= N_NODES) ar = N_NODES - 1;  // clamp loads; stores are guarded
    const unsigned short* aptr = xb + (long)ar * 128 + quad * 8;

    f32x4 acc2[4] = {};
#pragma unroll
    for (int s8 = 0; s8 < 8; ++s8) {
        short8 a;
        if (s8 < 4) {
            const int colb = (s8 * 64 + quad * 16) ^ ((rloc & 7) << 4);
            a = *(const short8*)((const char*)bt + rloc * 256 + colb);
        } else {
            a = *(const short8*)(aptr + (s8 - 4) * 32);
        }
#pragma unroll
        for (int t2 = 0; t2 < 4; ++t2) {
            const short8 bf =
                *(const short8*)(Wp + ((long)(s8 * 8 + wc * 4 + t2) * 64 + lane) * 8);
            acc2[t2] = __builtin_amdgcn_mfma_f32_16x16x32_bf16(a, bf, acc2[t2], 0, 0, 0);
        }
    }

    const int rowbase = row0 + wr * 16;
#pragma unroll
    for (int t2 = 0; t2 < 4; ++t2) {
        const int col = wc * 64 + t2 * 16 + lr;
        const float bvv = bv[col];
#pragma unroll
        for (int r = 0; r < 4; ++r) {
            const int row = rowbase + quad * 4 + r;
            if (row < N_NODES) out[(long)row * D + col] = acc2[t2][r] + bvv;
        }
    }
}

// ---------------------------------------------------------------------------
extern "C" void kernel_launch(void* const* d_in, const int* in_sizes, int n_in,
                              void* d_out, int out_size, void* d_ws, size_t ws_size,
                              hipStream_t stream) {
    const float* x  = (const float*)d_in[0];
    const int*   ei = (const int*)d_in[1];  // [2, E] flat: row0=src, row1=dst
    const float* Wc = (const float*)d_in[2];
    const float* bc = (const float*)d_in[3];
    const float* W0 = (const float*)d_in[4];
    const float* Wt = (const float*)d_in[5];
    float* out = (float*)d_out;

    const int* src = ei;
    const int* dst = ei + N_EDGES;

    // workspace layout:
    //   xb bf16 [N*128] | dinv f32 [N] | pbuf u32 [NB*CAPB] | bv f32 [D] |
    //   Wp bf16 [256*128] | gcur [NB]
    unsigned short* xb = (unsigned short*)d_ws;
    float* dinv        = (float*)(xb + (size_t)N_NODES * 128);
    unsigned int* pbuf = (unsigned int*)(dinv + N_NODES);
    float* bv          = (float*)(pbuf + (size_t)NB * CAPB);
    unsigned short* Wp = (unsigned short*)(bv + D);
    int* gcur          = (int*)(Wp + 256 * D);

    k_init<<<1, 1024, 0, stream>>>(gcur);
    k_a<<<KA_BLOCKS, 256, 0, stream>>>(src, dst, gcur, pbuf, Wc, W0, Wt, bc, x,
                                       Wp, bv, xb);
    k_deg<<<NB, 256, 0, stream>>>(pbuf, gcur, dinv);
    k_gmm<<<NB, 512, 0, stream>>>(xb, dinv, pbuf, gcur, Wp, bv, out);
}

// Round 5
// 219.686 us; speedup vs baseline: 3.8589x; 3.8589x over previous
//
#include <hip/hip_runtime.h>

#define N_NODES 50000
#define N_EDGES 800000
#define D 128
#define NB 391                 // buckets: bucket = dst >> 7, 128 nodes each
#define CAPB 4928              // fixed slots per bucket (mean 2046, ~64 sigma)
#define P1B 256                // partition blocks in k_a
#define EPB ((N_EDGES + P1B - 1) / P1B)  // 3125 edges/block
#define CAP 16                 // LDS staging slots per bucket in partition role
#define WPB 16                 // weight-pack blocks
#define XC0 (P1B + WPB + 1)    // first xcast block = 273
#define KA_BLOCKS (XC0 + (N_NODES * 16) / 256)  // 273 + 3125 = 3398

typedef __attribute__((ext_vector_type(8))) short short8;
typedef __attribute__((ext_vector_type(4))) float f32x4;

// round-to-nearest-even f32 -> bf16 (as ushort)
__device__ __forceinline__ unsigned short f2bf(float f) {
    unsigned int u = __builtin_bit_cast(unsigned int, f);
    u += 0x7FFFu + ((u >> 16) & 1u);
    return (unsigned short)(u >> 16);
}
__device__ __forceinline__ float bf2f(unsigned short h) {
    unsigned int u = ((unsigned int)h) << 16;
    return __builtin_bit_cast(float, u);
}

// ---------------------------------------------------------------------------
// gcur[b] = 0 (relative per-bucket fill counters; bases are fixed b*CAPB)
__global__ void k_init(int* __restrict__ gcur) {
    const int t = threadIdx.x;
    if (t < NB) gcur[t] = 0;
}

// ---------------------------------------------------------------------------
// Fused independent front-end (28 KB static LDS -> 5 blocks/CU):
//   blocks [0,256): edge partition into fixed-base buckets (LDS write-combine)
//   blocks [256,272): pack Wab = [Wc + Wc@Wt ; W0 - Wt] into bf16 B-fragments
//   block 272: bv = bc + bc@Wt
//   blocks [273,...): xb[n] = bf16(x[n])
__global__ __launch_bounds__(256) void k_a(const int* __restrict__ src,
                                           const int* __restrict__ dst,
                                           int* __restrict__ gcur,
                                           unsigned int* __restrict__ pbuf,
                                           const float* __restrict__ Wc,
                                           const float* __restrict__ W0,
                                           const float* __restrict__ Wt,
                                           const float* __restrict__ bc,
                                           const float* __restrict__ x,
                                           unsigned short* __restrict__ Wp,
                                           float* __restrict__ bv,
                                           unsigned short* __restrict__ xb) {
    __shared__ unsigned int stage[NB][CAP + 1];  // 26.6 KB (+1: conflict-free drain)
    __shared__ int scnt[NB];                     // 1.6 KB
    const int t = threadIdx.x;
    const unsigned int bid = blockIdx.x;

    if (bid < P1B) {  // ---- edge partition role ----
        for (int i = t; i < NB; i += 256) scnt[i] = 0;
        __syncthreads();

        const long e0 = (long)bid * EPB;
        const long e1 = (e0 + EPB < N_EDGES) ? e0 + EPB : N_EDGES;
        for (long e = e0 + t; e < e1; e += 256) {
            const int s = src[e];
            const int d = dst[e];
            const int b = d >> 7;
            const unsigned int p = ((unsigned int)(d & 127) << 16) | (unsigned int)s;
            const int slot = atomicAdd(&scnt[b], 1);
            if (slot < CAP) {
                stage[b][slot] = p;
            } else {  // spill (~1-2K edges total at CAP=16; correct for any dist)
                const int pos = atomicAdd(&gcur[b], 1);
                if (pos < CAPB) pbuf[(long)b * CAPB + pos] = p;
            }
        }
        __syncthreads();
        for (int bb = t; bb < NB; bb += 256) {
            const int n = (scnt[bb] < CAP) ? scnt[bb] : CAP;
            if (n > 0) {
                const int pos = atomicAdd(&gcur[bb], n);
                for (int i = 0; i < n; ++i)
                    if (pos + i < CAPB) pbuf[(long)bb * CAPB + pos + i] = stage[bb][i];
            }
        }
        return;
    }

    if (bid < P1B + WPB) {  // ---- weight pack role (L2-resident inputs) ----
        const int id = (int)(bid - P1B) * 256 + t;  // 0..4095
        const int lane = id & 63;
        const int tile = (id >> 6) & 7;
        const int step = id >> 9;
        const int n = tile * 16 + (lane & 15);
        const int kbase = step * 32 + (lane >> 4) * 8;
        float f[8];
#pragma unroll
        for (int j = 0; j < 8; ++j) {
            const int k = kbase + j;
            f[j] = (k < D) ? Wc[k * D + n]
                           : (W0[(k - D) * D + n] - Wt[(k - D) * D + n]);
        }
        if (kbase < D) {  // uniform per wave
#pragma unroll 8
            for (int m = 0; m < D; ++m) {
                const float wt = Wt[m * D + n];
#pragma unroll
                for (int j = 0; j < 8; ++j) f[j] += Wc[(kbase + j) * D + m] * wt;
            }
        }
        unsigned short v[8];
#pragma unroll
        for (int j = 0; j < 8; ++j) v[j] = f2bf(f[j]);
        *(uint4*)(Wp + (long)id * 8) = *(uint4*)v;
        return;
    }

    if (bid == P1B + WPB) {  // ---- bias role ----
        if (t < D) {
            float acc = bc[t];
#pragma unroll 16
            for (int k = 0; k < D; ++k) acc += bc[k] * Wt[k * D + t];
            bv[t] = acc;
        }
        return;
    }

    // ---- xcast role: xb = bf16(x) ----
    const int gid = (int)(bid - XC0) * 256 + t;  // 0 .. N*16-1
    const int node = gid >> 4;
    const int c = gid & 15;
    const float4 a = ((const float4*)x)[(long)node * 32 + c * 2];
    const float4 b = ((const float4*)x)[(long)node * 32 + c * 2 + 1];
    const float f[8] = {a.x, a.y, a.z, a.w, b.x, b.y, b.z, b.w};
    unsigned short vb[8];
#pragma unroll
    for (int j = 0; j < 8; ++j) vb[j] = f2bf(f[j]);
    *(uint4*)(xb + (long)node * 128 + c * 8) = *(uint4*)vb;
}

// ---------------------------------------------------------------------------
// Per-bucket local CSR build with SRC-RANGE counting sort.
// key = dst_local*4 + (src>>14): each node's edge list ends up ordered by 4
// coarse src ranges (~3.2 MB of xb each) -> k_gmm can sweep ranges machine-
// synchronously so the hot xb slice fits per-XCD L2.
// Outputs: row_start[node], cnt4[node] (4 packed u8 per-range counts),
//          dinv[node], esrc (range-sorted).
__global__ __launch_bounds__(256) void k_part2(const unsigned int* __restrict__ pbuf,
                                               const int* __restrict__ gcur,
                                               int* __restrict__ row_start,
                                               unsigned int* __restrict__ cnt4,
                                               float* __restrict__ dinv,
                                               int* __restrict__ esrc) {
    __shared__ int h[512];     // hist (counts stay intact)
    __shared__ int ps[256];    // pair sums for scan
    __shared__ int lcur[512];  // absolute scatter cursors (exclusive prefixes)
    const int b = blockIdx.x;
    const int t = threadIdx.x;
    const long base = (long)b * CAPB;
    int n = gcur[b];
    if (n > CAPB) n = CAPB;

    h[t] = 0;
    h[t + 256] = 0;
    __syncthreads();
    for (int i = t; i < n; i += 256) {
        const unsigned int p = pbuf[base + i];
        const int key = (int)((p >> 16) << 2) | (int)((p & 0xFFFFu) >> 14);
        atomicAdd(&h[key], 1);
    }
    __syncthreads();

    const int a0 = h[2 * t];
    const int a1 = h[2 * t + 1];
    ps[t] = a0 + a1;
    __syncthreads();
    for (int off = 1; off < 256; off <<= 1) {
        const int u = (t >= off) ? ps[t - off] : 0;
        __syncthreads();
        ps[t] += u;
        __syncthreads();
    }
    const int ep = ps[t] - a0 - a1;  // exclusive prefix of key 2t
    lcur[2 * t] = (int)base + ep;
    lcur[2 * t + 1] = (int)base + ep + a0;
    __syncthreads();

    if (t < 128) {
        const int node = b * 128 + t;
        if (node < N_NODES) {
            row_start[node] = lcur[4 * t];
            int c0 = h[4 * t], c1 = h[4 * t + 1], c2 = h[4 * t + 2], c3 = h[4 * t + 3];
            const int dg = c0 + c1 + c2 + c3;
            c0 = c0 > 255 ? 255 : c0;
            c1 = c1 > 255 ? 255 : c1;
            c2 = c2 > 255 ? 255 : c2;
            c3 = c3 > 255 ? 255 : c3;
            cnt4[node] = (unsigned)c0 | ((unsigned)c1 << 8) | ((unsigned)c2 << 16) |
                         ((unsigned)c3 << 24);
            dinv[node] = rsqrtf((float)dg + 1.0f);
        }
    }
    __syncthreads();

    for (int i = t; i < n; i += 256) {
        const unsigned int p = pbuf[base + i];
        const int key = (int)((p >> 16) << 2) | (int)((p & 0xFFFFu) >> 14);
        const int pos = atomicAdd(&lcur[key], 1);
        esrc[pos] = (int)(p & 0xFFFFu);
    }
}

// ---------------------------------------------------------------------------
// Fused gather + GEMM. Block = 64 rows, 512 threads = 8 waves.
// Phase 1 (gather, range-synchronized): each wave owns 8 nodes with all 8
//   accumulator sets live (acc[8][8] in regs). Outer loop = 4 src-ranges; all
//   waves sweep range r together -> xb slice (~3.2 MB) is per-XCD-L2-resident.
//   Per chunk-step: 8 independent predicated row loads (safe addr = row 0,
//   an L1 hit, so padding doesn't consume miss-queue slots).
// Phase 2: shuffle-reduce, self-term, dinv scale, bf16 XOR-swizzled LDS tile.
// Phase 3: wave (wr,wc): rows wr*16..+15, cols wc*64..+63 of
//   [64x256] @ Wab[256x128]: k 0..127 from LDS tile, k 128..255 from xb.
__global__ __launch_bounds__(512) void k_gmm(const unsigned short* __restrict__ xb,
                                             const int* __restrict__ row_start,
                                             const unsigned int* __restrict__ cnt4,
                                             const float* __restrict__ dinv,
                                             const int* __restrict__ esrc,
                                             const unsigned short* __restrict__ Wp,
                                             const float* __restrict__ bv,
                                             float* __restrict__ out) {
    __shared__ unsigned short sg[64 * 128];  // 16 KB, rows XOR-swizzled
    const int tid = threadIdx.x;
    const int wave = tid >> 6;  // 0..7
    const int lane = tid & 63;
    const int c = lane & 15;  // 8-elem chunk
    const int s = lane >> 4;  // edge slot
    const int row0 = blockIdx.x * 64;

    int cur[8];
    unsigned int cc[8];
    float acc[8][8];
#pragma unroll
    for (int m = 0; m < 8; ++m) {
        const int node = row0 + wave * 8 + m;
        const bool v = node < N_NODES;
        cur[m] = v ? row_start[node] : 0;
        cc[m] = v ? cnt4[node] : 0u;
#pragma unroll
        for (int j = 0; j < 8; ++j) acc[m][j] = 0.0f;
    }

#pragma unroll
    for (int r = 0; r < 4; ++r) {
        int cN[8];
        int mxc = 0;
#pragma unroll
        for (int m = 0; m < 8; ++m) {
            cN[m] = (int)((cc[m] >> (8 * r)) & 255u);
            mxc = (cN[m] > mxc) ? cN[m] : mxc;
        }
        for (int k0 = 0; k0 < mxc; k0 += 4) {
            const int kk = k0 + s;
            int a[8];
            float w[8];
#pragma unroll
            for (int m = 0; m < 8; ++m) {
                const bool ok = kk < cN[m];
                a[m] = ok ? esrc[cur[m] + kk] : 0;
                w[m] = ok ? 1.0f : 0.0f;
            }
            float d[8];
#pragma unroll
            for (int m = 0; m < 8; ++m) d[m] = w[m] * dinv[a[m]];
            short8 v[8];
#pragma unroll
            for (int m = 0; m < 8; ++m)
                v[m] = *(const short8*)(xb + (long)a[m] * 128 + c * 8);
#pragma unroll
            for (int m = 0; m < 8; ++m)
#pragma unroll
                for (int j = 0; j < 8; ++j)
                    acc[m][j] += d[m] * bf2f((unsigned short)v[m][j]);
        }
#pragma unroll
        for (int m = 0; m < 8; ++m) cur[m] += cN[m];
    }

    // phase 2: reduce across slots, self term, scale, swizzled bf16 store
#pragma unroll
    for (int m = 0; m < 8; ++m) {
        float t8[8];
#pragma unroll
        for (int j = 0; j < 8; ++j) {
            float v = acc[m][j];
            v += __shfl_xor(v, 16);
            v += __shfl_xor(v, 32);
            t8[j] = v;
        }
        if (s == 0) {
            const int r = wave * 8 + m;  // LDS row
            const int node = row0 + r;
            unsigned short o[8] = {0, 0, 0, 0, 0, 0, 0, 0};
            if (node < N_NODES) {
                const float di = dinv[node];
                const short8 xs = *(const short8*)(xb + (long)node * 128 + c * 8);
#pragma unroll
                for (int j = 0; j < 8; ++j)
                    o[j] = f2bf(di * (t8[j] + di * bf2f((unsigned short)xs[j])));
            }
            const int col = (c * 16) ^ ((r & 7) << 4);  // swizzled byte offset
            *(uint4*)((char*)sg + r * 256 + col) = *(uint4*)o;
        }
    }
    __syncthreads();

    // ---- phase 3: GEMM. wave (wr,wc) -> rows wr*16..+15, cols wc*64..+63 ----
    const int lr = lane & 15;
    const int quad = lane >> 4;
    const int wr = wave & 3;
    const int wc = wave >> 2;
    const int rloc = wr * 16 + lr;  // LDS row this lane reads
    int ar = row0 + rloc;
    if (ar >= N_NODES) ar = N_NODES - 1;  // clamp loads; stores are guarded
    const unsigned short* aptr = xb + (long)ar * 128 + quad * 8;

    f32x4 acc2[4] = {};
#pragma unroll
    for (int s8 = 0; s8 < 8; ++s8) {
        short8 afrag;
        if (s8 < 4) {
            const int colb = (s8 * 64 + quad * 16) ^ ((rloc & 7) << 4);
            afrag = *(const short8*)((const char*)sg + rloc * 256 + colb);
        } else {
            afrag = *(const short8*)(aptr + (s8 - 4) * 32);
        }
#pragma unroll
        for (int t2 = 0; t2 < 4; ++t2) {
            const short8 bfrag =
                *(const short8*)(Wp + ((long)(s8 * 8 + wc * 4 + t2) * 64 + lane) * 8);
            acc2[t2] =
                __builtin_amdgcn_mfma_f32_16x16x32_bf16(afrag, bfrag, acc2[t2], 0, 0, 0);
        }
    }

    const int rowbase = row0 + wr * 16;
#pragma unroll
    for (int t2 = 0; t2 < 4; ++t2) {
        const int col = wc * 64 + t2 * 16 + lr;
        const float bvv = bv[col];
#pragma unroll
        for (int r = 0; r < 4; ++r) {
            const int row = rowbase + quad * 4 + r;
            if (row < N_NODES) out[(long)row * D + col] = acc2[t2][r] + bvv;
        }
    }
}

// ---------------------------------------------------------------------------
extern "C" void kernel_launch(void* const* d_in, const int* in_sizes, int n_in,
                              void* d_out, int out_size, void* d_ws, size_t ws_size,
                              hipStream_t stream) {
    const float* x  = (const float*)d_in[0];
    const int*   ei = (const int*)d_in[1];  // [2, E] flat: row0=src, row1=dst
    const float* Wc = (const float*)d_in[2];
    const float* bc = (const float*)d_in[3];
    const float* W0 = (const float*)d_in[4];
    const float* Wt = (const float*)d_in[5];
    float* out = (float*)d_out;

    const int* src = ei;
    const int* dst = ei + N_EDGES;

    // workspace layout:
    //   xb bf16 [N*128] | row_start [N] | cnt4 u32 [N] | dinv f32 [N] |
    //   esrc [NB*CAPB] | pbuf [NB*CAPB] | bv f32 [D] | Wp bf16 [256*128] | gcur [NB]
    unsigned short* xb  = (unsigned short*)d_ws;
    int* row_start      = (int*)(xb + (size_t)N_NODES * 128);
    unsigned int* cnt4  = (unsigned int*)(row_start + N_NODES);
    float* dinv         = (float*)(cnt4 + N_NODES);
    int* esrc           = (int*)(dinv + N_NODES);
    unsigned int* pbuf  = (unsigned int*)(esrc + (size_t)NB * CAPB);
    float* bv           = (float*)(pbuf + (size_t)NB * CAPB);
    unsigned short* Wp  = (unsigned short*)(bv + D);
    int* gcur           = (int*)(Wp + 256 * D);

    k_init<<<1, 512, 0, stream>>>(gcur);
    k_a<<<KA_BLOCKS, 256, 0, stream>>>(src, dst, gcur, pbuf, Wc, W0, Wt, bc, x,
                                       Wp, bv, xb);
    k_part2<<<NB, 256, 0, stream>>>(pbuf, gcur, row_start, cnt4, dinv, esrc);
    k_gmm<<<(N_NODES + 63) / 64, 512, 0, stream>>>(xb, row_start, cnt4, dinv, esrc,
                                                   Wp, bv, out);
}

// Round 6
// 177.878 us; speedup vs baseline: 4.7658x; 1.2350x over previous
//
#include <hip/hip_runtime.h>

#define N_NODES 50000
#define N_EDGES 800000
#define D 128
#define NB 391                 // buckets: bucket = dst >> 7, 128 nodes each
#define CAPB 4928              // fixed slots per bucket (mean 2046, ~64 sigma)
#define P1B 256                // partition blocks in k_a
#define EPB ((N_EDGES + P1B - 1) / P1B)  // 3125 edges/block
#define CAP 16                 // LDS staging slots per bucket in partition role
#define WPB 16                 // weight-pack blocks
#define XC0 (P1B + WPB + 1)    // first xcast block = 273
#define KA_BLOCKS (XC0 + (N_NODES * 16) / 256)  // 273 + 3125 = 3398

typedef __attribute__((ext_vector_type(8))) short short8;
typedef __attribute__((ext_vector_type(8))) char char8;
typedef __attribute__((ext_vector_type(4))) float f32x4;

// round-to-nearest-even f32 -> bf16 (as ushort)
__device__ __forceinline__ unsigned short f2bf(float f) {
    unsigned int u = __builtin_bit_cast(unsigned int, f);
    u += 0x7FFFu + ((u >> 16) & 1u);
    return (unsigned short)(u >> 16);
}
__device__ __forceinline__ float bf2f(unsigned short h) {
    unsigned int u = ((unsigned int)h) << 16;
    return __builtin_bit_cast(float, u);
}

// ---------------------------------------------------------------------------
// gcur[b] = 0 (relative per-bucket fill counters; bases are fixed b*CAPB)
__global__ void k_init(int* __restrict__ gcur) {
    const int t = threadIdx.x;
    if (t < NB) gcur[t] = 0;
}

// ---------------------------------------------------------------------------
// Fused independent front-end (28 KB static LDS -> 5 blocks/CU):
//   blocks [0,256): edge partition into fixed-base buckets (LDS write-combine)
//   blocks [256,272): pack Wab = [Wc + Wc@Wt ; W0 - Wt] into bf16 B-fragments
//   block 272: bv = bc + bc@Wt
//   blocks [273,...): xb[n] = bf16(x[n]); qx[n] = int8 row-quant; wsc[n] = scale
__global__ __launch_bounds__(256) void k_a(const int* __restrict__ src,
                                           const int* __restrict__ dst,
                                           int* __restrict__ gcur,
                                           unsigned int* __restrict__ pbuf,
                                           const float* __restrict__ Wc,
                                           const float* __restrict__ W0,
                                           const float* __restrict__ Wt,
                                           const float* __restrict__ bc,
                                           const float* __restrict__ x,
                                           unsigned short* __restrict__ Wp,
                                           float* __restrict__ bv,
                                           unsigned short* __restrict__ xb,
                                           char* __restrict__ qx,
                                           float* __restrict__ wsc) {
    __shared__ unsigned int stage[NB][CAP + 1];  // 26.6 KB (+1: conflict-free drain)
    __shared__ int scnt[NB];                     // 1.6 KB
    const int t = threadIdx.x;
    const unsigned int bid = blockIdx.x;

    if (bid < P1B) {  // ---- edge partition role ----
        for (int i = t; i < NB; i += 256) scnt[i] = 0;
        __syncthreads();

        const long e0 = (long)bid * EPB;
        const long e1 = (e0 + EPB < N_EDGES) ? e0 + EPB : N_EDGES;
        for (long e = e0 + t; e < e1; e += 256) {
            const int s = src[e];
            const int d = dst[e];
            const int b = d >> 7;
            const unsigned int p = ((unsigned int)(d & 127) << 16) | (unsigned int)s;
            const int slot = atomicAdd(&scnt[b], 1);
            if (slot < CAP) {
                stage[b][slot] = p;
            } else {  // spill (~1-2K edges total at CAP=16; correct for any dist)
                const int pos = atomicAdd(&gcur[b], 1);
                if (pos < CAPB) pbuf[(long)b * CAPB + pos] = p;
            }
        }
        __syncthreads();
        for (int bb = t; bb < NB; bb += 256) {
            const int n = (scnt[bb] < CAP) ? scnt[bb] : CAP;
            if (n > 0) {
                const int pos = atomicAdd(&gcur[bb], n);
                for (int i = 0; i < n; ++i)
                    if (pos + i < CAPB) pbuf[(long)bb * CAPB + pos + i] = stage[bb][i];
            }
        }
        return;
    }

    if (bid < P1B + WPB) {  // ---- weight pack role (L2-resident inputs) ----
        const int id = (int)(bid - P1B) * 256 + t;  // 0..4095
        const int lane = id & 63;
        const int tile = (id >> 6) & 7;
        const int step = id >> 9;
        const int n = tile * 16 + (lane & 15);
        const int kbase = step * 32 + (lane >> 4) * 8;
        float f[8];
#pragma unroll
        for (int j = 0; j < 8; ++j) {
            const int k = kbase + j;
            f[j] = (k < D) ? Wc[k * D + n]
                           : (W0[(k - D) * D + n] - Wt[(k - D) * D + n]);
        }
        if (kbase < D) {  // uniform per wave
#pragma unroll 8
            for (int m = 0; m < D; ++m) {
                const float wt = Wt[m * D + n];
#pragma unroll
                for (int j = 0; j < 8; ++j) f[j] += Wc[(kbase + j) * D + m] * wt;
            }
        }
        unsigned short v[8];
#pragma unroll
        for (int j = 0; j < 8; ++j) v[j] = f2bf(f[j]);
        *(uint4*)(Wp + (long)id * 8) = *(uint4*)v;
        return;
    }

    if (bid == P1B + WPB) {  // ---- bias role ----
        if (t < D) {
            float acc = bc[t];
#pragma unroll 16
            for (int k = 0; k < D; ++k) acc += bc[k] * Wt[k * D + t];
            bv[t] = acc;
        }
        return;
    }

    // ---- xcast role: xb = bf16(x); qx = int8 row-absmax quant; wsc = scale ----
    const int gid = (int)(bid - XC0) * 256 + t;  // 0 .. N*16-1
    const int node = gid >> 4;
    const int c = gid & 15;
    const float4 a = ((const float4*)x)[(long)node * 32 + c * 2];
    const float4 b = ((const float4*)x)[(long)node * 32 + c * 2 + 1];
    const float f[8] = {a.x, a.y, a.z, a.w, b.x, b.y, b.z, b.w};
    unsigned short vb[8];
    float mx = 0.0f;
#pragma unroll
    for (int j = 0; j < 8; ++j) {
        vb[j] = f2bf(f[j]);
        const float af = fabsf(f[j]);
        mx = af > mx ? af : mx;
    }
    *(uint4*)(xb + (long)node * 128 + c * 8) = *(uint4*)vb;
    // row absmax across the 16-lane group (nodes are 16-lane-aligned in wave)
#pragma unroll
    for (int m = 1; m < 16; m <<= 1) {
        const float o = __shfl_xor(mx, m);
        mx = o > mx ? o : mx;
    }
    const float inv = (mx > 0.0f) ? 127.0f / mx : 0.0f;
    unsigned int w0 = 0, w1 = 0;
#pragma unroll
    for (int j = 0; j < 4; ++j) {
        const int q = (int)__builtin_rintf(f[j] * inv);
        w0 |= ((unsigned int)(q & 255)) << (8 * j);
    }
#pragma unroll
    for (int j = 0; j < 4; ++j) {
        const int q = (int)__builtin_rintf(f[4 + j] * inv);
        w1 |= ((unsigned int)(q & 255)) << (8 * j);
    }
    uint2 qp;
    qp.x = w0;
    qp.y = w1;
    *(uint2*)(qx + (long)node * 128 + c * 8) = qp;
    if (c == 0) wsc[node] = (mx > 0.0f) ? mx * (1.0f / 127.0f) : 0.0f;
}

// ---------------------------------------------------------------------------
// Per-bucket local CSR build (128-node buckets): hist + scan in LDS, scatter
// into L2-local window. Produces row_start / cnt / dinv / wsd (=dinv*wsc).
__global__ __launch_bounds__(256) void k_part2(const unsigned int* __restrict__ pbuf,
                                               const int* __restrict__ gcur,
                                               const float* __restrict__ wsc,
                                               int* __restrict__ row_start,
                                               int* __restrict__ cnt,
                                               float* __restrict__ dinv,
                                               float* __restrict__ wsd,
                                               int* __restrict__ esrc) {
    __shared__ int lcnt[128];
    __shared__ int lcur[128];
    __shared__ int stmp[128];
    const int b = blockIdx.x;
    const int t = threadIdx.x;
    const int base = b * CAPB;
    int n = gcur[b];  // relative count
    if (n > CAPB) n = CAPB;

    if (t < 128) lcnt[t] = 0;
    __syncthreads();
    for (int i = t; i < n; i += 256) atomicAdd(&lcnt[pbuf[base + i] >> 16], 1);
    __syncthreads();

    int c = 0;
    if (t < 128) {
        c = lcnt[t];
        stmp[t] = c;
    }
    __syncthreads();
    for (int off = 1; off < 128; off <<= 1) {
        int u = (t >= off && t < 128) ? stmp[t - off] : 0;
        __syncthreads();
        if (t < 128) stmp[t] += u;
        __syncthreads();
    }
    if (t < 128) {
        const int ls = base + stmp[t] - c;  // exclusive, within bucket window
        lcur[t] = ls;
        const int node = b * 128 + t;
        if (node < N_NODES) {
            row_start[node] = ls;
            cnt[node] = c;
            const float di = rsqrtf((float)c + 1.0f);
            dinv[node] = di;
            wsd[node] = di * wsc[node];  // fused dequant+norm weight for gather
        }
    }
    __syncthreads();

    for (int i = t; i < n; i += 256) {
        const unsigned int p = pbuf[base + i];
        const int pos = atomicAdd(&lcur[p >> 16], 1);
        esrc[pos] = (int)(p & 0xFFFFu);
    }
}

// ---------------------------------------------------------------------------
// Fused gather + GEMM. Block = 64 rows, 512 threads = 8 waves.
// Phase 1: wave w gathers nodes w*8..w*8+7 from the int8 qx rows (128 B/edge =
//          2 cache lines, half the round-2 line count); per-edge weight
//          wsd[src] = dinv[src]*scale[src]. Self term from bf16 xb.
//          Result -> bf16 XOR-swizzled LDS tile.
// Phase 2: wave w=(wr,wc) computes rows wr*16..+15, cols wc*64..+63 of
//          [64x256] @ Wab[256x128]: k 0..127 from LDS (g), k 128..255 from xb.
__global__ __launch_bounds__(512) void k_gmm(const unsigned short* __restrict__ xb,
                                             const char* __restrict__ qx,
                                             const int* __restrict__ row_start,
                                             const int* __restrict__ cnt,
                                             const float* __restrict__ dinv,
                                             const float* __restrict__ wsd,
                                             const int* __restrict__ esrc,
                                             const unsigned short* __restrict__ Wp,
                                             const float* __restrict__ bv,
                                             float* __restrict__ out) {
    __shared__ unsigned short sg[64 * 128];  // 16 KB, rows XOR-swizzled
    const int tid = threadIdx.x;
    const int wave = tid >> 6;  // 0..7
    const int lane = tid & 63;
    const int c = lane & 15;  // 8-elem chunk
    const int s = lane >> 4;  // edge slot
    const int row0 = blockIdx.x * 64;

    // hoist row ranges for this wave's 8 nodes (fully unrolled -> registers)
    int beg[8], en[8];
#pragma unroll
    for (int m = 0; m < 8; ++m) {
        const int node = row0 + wave * 8 + m;
        const bool v = node < N_NODES;
        const int b0 = v ? row_start[node] : 0;
        beg[m] = b0;
        en[m] = b0 + (v ? cnt[node] : 0);
    }

#pragma unroll
    for (int m = 0; m < 8; ++m) {
        const int node = row0 + wave * 8 + m;
        const bool valid = node < N_NODES;
        float acc[8] = {};
        int i = beg[m] + s;
        const int end = en[m];
        for (; i + 12 < end; i += 16) {  // four edges in flight per slot
            const int a0 = esrc[i];
            const int a1 = esrc[i + 4];
            const int a2 = esrc[i + 8];
            const int a3 = esrc[i + 12];
            const char8 v0 = *(const char8*)(qx + (long)a0 * 128 + c * 8);
            const char8 v1 = *(const char8*)(qx + (long)a1 * 128 + c * 8);
            const char8 v2 = *(const char8*)(qx + (long)a2 * 128 + c * 8);
            const char8 v3 = *(const char8*)(qx + (long)a3 * 128 + c * 8);
            const float d0 = wsd[a0];
            const float d1 = wsd[a1];
            const float d2 = wsd[a2];
            const float d3 = wsd[a3];
#pragma unroll
            for (int j = 0; j < 8; ++j)
                acc[j] += (d0 * (float)v0[j] + d1 * (float)v1[j]) +
                          (d2 * (float)v2[j] + d3 * (float)v3[j]);
        }
        for (; i < end; i += 4) {
            const int a0 = esrc[i];
            const float d0 = wsd[a0];
            const char8 v0 = *(const char8*)(qx + (long)a0 * 128 + c * 8);
#pragma unroll
            for (int j = 0; j < 8; ++j) acc[j] += d0 * (float)v0[j];
        }
#pragma unroll
        for (int j = 0; j < 8; ++j) {
            acc[j] += __shfl_xor(acc[j], 16);
            acc[j] += __shfl_xor(acc[j], 32);
        }
        if (s == 0) {
            const int r = wave * 8 + m;  // LDS row
            unsigned short o[8] = {0, 0, 0, 0, 0, 0, 0, 0};
            if (valid) {
                const float di = dinv[node];
                const short8 xs = *(const short8*)(xb + (long)node * 128 + c * 8);
#pragma unroll
                for (int j = 0; j < 8; ++j)
                    o[j] = f2bf(di * (acc[j] + di * bf2f((unsigned short)xs[j])));
            }
            const int col = (c * 16) ^ ((r & 7) << 4);  // swizzled byte offset
            *(uint4*)((char*)sg + r * 256 + col) = *(uint4*)o;
        }
    }
    __syncthreads();

    // ---- GEMM phase: wave (wr,wc) -> rows wr*16..+15, cols wc*64..+63 ----
    const int lr = lane & 15;
    const int quad = lane >> 4;
    const int wr = wave & 3;
    const int wc = wave >> 2;
    const int rloc = wr * 16 + lr;  // LDS row this lane reads
    int ar = row0 + rloc;
    if (ar >= N_NODES) ar = N_NODES - 1;  // clamp loads; stores are guarded
    const unsigned short* aptr = xb + (long)ar * 128 + quad * 8;

    f32x4 acc2[4] = {};
#pragma unroll
    for (int s8 = 0; s8 < 8; ++s8) {
        short8 a;
        if (s8 < 4) {
            const int colb = (s8 * 64 + quad * 16) ^ ((rloc & 7) << 4);
            a = *(const short8*)((const char*)sg + rloc * 256 + colb);
        } else {
            a = *(const short8*)(aptr + (s8 - 4) * 32);
        }
#pragma unroll
        for (int t2 = 0; t2 < 4; ++t2) {
            const short8 b =
                *(const short8*)(Wp + ((long)(s8 * 8 + wc * 4 + t2) * 64 + lane) * 8);
            acc2[t2] = __builtin_amdgcn_mfma_f32_16x16x32_bf16(a, b, acc2[t2], 0, 0, 0);
        }
    }

    const int rowbase = row0 + wr * 16;
#pragma unroll
    for (int t2 = 0; t2 < 4; ++t2) {
        const int col = wc * 64 + t2 * 16 + lr;
        const float bvv = bv[col];
#pragma unroll
        for (int r = 0; r < 4; ++r) {
            const int row = rowbase + quad * 4 + r;
            if (row < N_NODES) out[(long)row * D + col] = acc2[t2][r] + bvv;
        }
    }
}

// ---------------------------------------------------------------------------
extern "C" void kernel_launch(void* const* d_in, const int* in_sizes, int n_in,
                              void* d_out, int out_size, void* d_ws, size_t ws_size,
                              hipStream_t stream) {
    const float* x  = (const float*)d_in[0];
    const int*   ei = (const int*)d_in[1];  // [2, E] flat: row0=src, row1=dst
    const float* Wc = (const float*)d_in[2];
    const float* bc = (const float*)d_in[3];
    const float* W0 = (const float*)d_in[4];
    const float* Wt = (const float*)d_in[5];
    float* out = (float*)d_out;

    const int* src = ei;
    const int* dst = ei + N_EDGES;

    // workspace layout:
    //   xb bf16 [N*128] | qx i8 [N*128] | row_start [N] | cnt [N] | dinv [N] |
    //   wsc [N] | wsd [N] | esrc [NB*CAPB] | pbuf [NB*CAPB] | bv f32 [D] |
    //   Wp bf16 [256*128] | gcur [NB]
    unsigned short* xb = (unsigned short*)d_ws;
    char* qx          = (char*)(xb + (size_t)N_NODES * 128);
    int*   row_start  = (int*)(qx + (size_t)N_NODES * 128);
    int*   cnt        = row_start + N_NODES;
    float* dinv       = (float*)(cnt + N_NODES);
    float* wsc        = dinv + N_NODES;
    float* wsd        = wsc + N_NODES;
    int*   esrc       = (int*)(wsd + N_NODES);
    unsigned int* pbuf = (unsigned int*)(esrc + (size_t)NB * CAPB);
    float* bv         = (float*)(pbuf + (size_t)NB * CAPB);
    unsigned short* Wp = (unsigned short*)(bv + D);
    int*   gcur       = (int*)(Wp + 256 * D);

    k_init<<<1, 512, 0, stream>>>(gcur);
    k_a<<<KA_BLOCKS, 256, 0, stream>>>(src, dst, gcur, pbuf, Wc, W0, Wt, bc, x,
                                       Wp, bv, xb, qx, wsc);
    k_part2<<<NB, 256, 0, stream>>>(pbuf, gcur, wsc, row_start, cnt, dinv, wsd, esrc);
    k_gmm<<<(N_NODES + 63) / 64, 512, 0, stream>>>(xb, qx, row_start, cnt, dinv, wsd,
                                                   esrc, Wp, bv, out);
}

// Round 8
// 174.513 us; speedup vs baseline: 4.8577x; 1.0193x over previous
//
#include <hip/hip_runtime.h>

#define N_NODES 50000
#define N_EDGES 800000
#define D 128
#define NB 391                 // buckets: bucket = dst >> 7, 128 nodes each
#define CAPB 4928              // fixed slots per bucket (mean 2046, ~64 sigma)
#define P1B 256                // partition blocks in k_a
#define EPB ((N_EDGES + P1B - 1) / P1B)  // 3125 edges/block
#define CAP 16                 // LDS staging slots per bucket in partition role
#define WPB 16                 // weight-pack blocks
#define XC0 (P1B + WPB + 1)    // first xcast block = 273
#define KA_BLOCKS (XC0 + (N_NODES * 16) / 256)  // 273 + 3125 = 3398

typedef __attribute__((ext_vector_type(8))) short short8;
typedef __attribute__((ext_vector_type(4))) float f32x4;

// round-to-nearest-even f32 -> bf16 (as ushort)
__device__ __forceinline__ unsigned short f2bf(float f) {
    unsigned int u = __builtin_bit_cast(unsigned int, f);
    u += 0x7FFFu + ((u >> 16) & 1u);
    return (unsigned short)(u >> 16);
}
__device__ __forceinline__ float bf2f(unsigned short h) {
    unsigned int u = ((unsigned int)h) << 16;
    return __builtin_bit_cast(float, u);
}

// accumulate 16 int8 elements (one uint4 = 16 bytes) with weight w
#define GACC(Q, W)                                                              \
    {                                                                           \
        const int qd0 = (int)(Q).x, qd1 = (int)(Q).y;                           \
        const int qd2 = (int)(Q).z, qd3 = (int)(Q).w;                           \
        _Pragma("unroll") for (int bb = 0; bb < 4; ++bb) {                      \
            acc[bb] += (W) * (float)((signed char)(qd0 >> (8 * bb)));           \
            acc[4 + bb] += (W) * (float)((signed char)(qd1 >> (8 * bb)));       \
            acc[8 + bb] += (W) * (float)((signed char)(qd2 >> (8 * bb)));       \
            acc[12 + bb] += (W) * (float)((signed char)(qd3 >> (8 * bb)));      \
        }                                                                       \
    }

// ---------------------------------------------------------------------------
// gcur[b] = 0 (relative per-bucket fill counters; bases are fixed b*CAPB)
__global__ void k_init(int* __restrict__ gcur) {
    const int t = threadIdx.x;
    if (t < NB) gcur[t] = 0;
}

// ---------------------------------------------------------------------------
// Fused independent front-end (28 KB static LDS -> 5 blocks/CU):
//   blocks [0,256): edge partition into fixed-base buckets (LDS write-combine)
//   blocks [256,272): pack Wab = [Wc + Wc@Wt ; W0 - Wt] into bf16 B-fragments
//   block 272: bv = bc + bc@Wt
//   blocks [273,...): xb[n] = bf16(x[n]); qx[n] = int8 row-quant; wsc[n] = scale
__global__ __launch_bounds__(256) void k_a(const int* __restrict__ src,
                                           const int* __restrict__ dst,
                                           int* __restrict__ gcur,
                                           unsigned int* __restrict__ pbuf,
                                           const float* __restrict__ Wc,
                                           const float* __restrict__ W0,
                                           const float* __restrict__ Wt,
                                           const float* __restrict__ bc,
                                           const float* __restrict__ x,
                                           unsigned short* __restrict__ Wp,
                                           float* __restrict__ bv,
                                           unsigned short* __restrict__ xb,
                                           char* __restrict__ qx,
                                           float* __restrict__ wsc) {
    __shared__ unsigned int stage[NB][CAP + 1];  // 26.6 KB (+1: conflict-free drain)
    __shared__ int scnt[NB];                     // 1.6 KB
    const int t = threadIdx.x;
    const unsigned int bid = blockIdx.x;

    if (bid < P1B) {  // ---- edge partition role ----
        for (int i = t; i < NB; i += 256) scnt[i] = 0;
        __syncthreads();

        const long e0 = (long)bid * EPB;
        const long e1 = (e0 + EPB < N_EDGES) ? e0 + EPB : N_EDGES;
        for (long e = e0 + t; e < e1; e += 256) {
            const int s = src[e];
            const int d = dst[e];
            const int b = d >> 7;
            const unsigned int p = ((unsigned int)(d & 127) << 16) | (unsigned int)s;
            const int slot = atomicAdd(&scnt[b], 1);
            if (slot < CAP) {
                stage[b][slot] = p;
            } else {  // spill (~1-2K edges total at CAP=16; correct for any dist)
                const int pos = atomicAdd(&gcur[b], 1);
                if (pos < CAPB) pbuf[(long)b * CAPB + pos] = p;
            }
        }
        __syncthreads();
        for (int bb = t; bb < NB; bb += 256) {
            const int n = (scnt[bb] < CAP) ? scnt[bb] : CAP;
            if (n > 0) {
                const int pos = atomicAdd(&gcur[bb], n);
                for (int i = 0; i < n; ++i)
                    if (pos + i < CAPB) pbuf[(long)bb * CAPB + pos + i] = stage[bb][i];
            }
        }
        return;
    }

    if (bid < P1B + WPB) {  // ---- weight pack role (L2-resident inputs) ----
        const int id = (int)(bid - P1B) * 256 + t;  // 0..4095
        const int lane = id & 63;
        const int tile = (id >> 6) & 7;
        const int step = id >> 9;
        const int n = tile * 16 + (lane & 15);
        const int kbase = step * 32 + (lane >> 4) * 8;
        float f[8];
#pragma unroll
        for (int j = 0; j < 8; ++j) {
            const int k = kbase + j;
            f[j] = (k < D) ? Wc[k * D + n]
                           : (W0[(k - D) * D + n] - Wt[(k - D) * D + n]);
        }
        if (kbase < D) {  // uniform per wave
#pragma unroll 8
            for (int m = 0; m < D; ++m) {
                const float wt = Wt[m * D + n];
#pragma unroll
                for (int j = 0; j < 8; ++j) f[j] += Wc[(kbase + j) * D + m] * wt;
            }
        }
        unsigned short v[8];
#pragma unroll
        for (int j = 0; j < 8; ++j) v[j] = f2bf(f[j]);
        *(uint4*)(Wp + (long)id * 8) = *(uint4*)v;
        return;
    }

    if (bid == P1B + WPB) {  // ---- bias role ----
        if (t < D) {
            float acc = bc[t];
#pragma unroll 16
            for (int k = 0; k < D; ++k) acc += bc[k] * Wt[k * D + t];
            bv[t] = acc;
        }
        return;
    }

    // ---- xcast role: xb = bf16(x); qx = int8 row-absmax quant; wsc = scale ----
    const int gid = (int)(bid - XC0) * 256 + t;  // 0 .. N*16-1
    const int node = gid >> 4;
    const int c = gid & 15;
    const float4 a = ((const float4*)x)[(long)node * 32 + c * 2];
    const float4 b = ((const float4*)x)[(long)node * 32 + c * 2 + 1];
    const float f[8] = {a.x, a.y, a.z, a.w, b.x, b.y, b.z, b.w};
    unsigned short vb[8];
    float mx = 0.0f;
#pragma unroll
    for (int j = 0; j < 8; ++j) {
        vb[j] = f2bf(f[j]);
        const float af = fabsf(f[j]);
        mx = af > mx ? af : mx;
    }
    *(uint4*)(xb + (long)node * 128 + c * 8) = *(uint4*)vb;
    // row absmax across the 16-lane group (nodes are 16-lane-aligned in wave)
#pragma unroll
    for (int m = 1; m < 16; m <<= 1) {
        const float o = __shfl_xor(mx, m);
        mx = o > mx ? o : mx;
    }
    const float inv = (mx > 0.0f) ? 127.0f / mx : 0.0f;
    unsigned int w0 = 0, w1 = 0;
#pragma unroll
    for (int j = 0; j < 4; ++j) {
        const int q = (int)__builtin_rintf(f[j] * inv);
        w0 |= ((unsigned int)(q & 255)) << (8 * j);
    }
#pragma unroll
    for (int j = 0; j < 4; ++j) {
        const int q = (int)__builtin_rintf(f[4 + j] * inv);
        w1 |= ((unsigned int)(q & 255)) << (8 * j);
    }
    uint2 qp;
    qp.x = w0;
    qp.y = w1;
    *(uint2*)(qx + (long)node * 128 + c * 8) = qp;
    if (c == 0) wsc[node] = (mx > 0.0f) ? mx * (1.0f / 127.0f) : 0.0f;
}

// ---------------------------------------------------------------------------
// Per-bucket local CSR build (128-node buckets): hist + scan in LDS, scatter
// into L2-local window. Produces row_start / cnt / dinv / wsd (=dinv*wsc).
__global__ __launch_bounds__(256) void k_part2(const unsigned int* __restrict__ pbuf,
                                               const int* __restrict__ gcur,
                                               const float* __restrict__ wsc,
                                               int* __restrict__ row_start,
                                               int* __restrict__ cnt,
                                               float* __restrict__ dinv,
                                               float* __restrict__ wsd,
                                               int* __restrict__ esrc) {
    __shared__ int lcnt[128];
    __shared__ int lcur[128];
    __shared__ int stmp[128];
    const int b = blockIdx.x;
    const int t = threadIdx.x;
    const int base = b * CAPB;
    int n = gcur[b];  // relative count
    if (n > CAPB) n = CAPB;

    if (t < 128) lcnt[t] = 0;
    __syncthreads();
    for (int i = t; i < n; i += 256) atomicAdd(&lcnt[pbuf[base + i] >> 16], 1);
    __syncthreads();

    int c = 0;
    if (t < 128) {
        c = lcnt[t];
        stmp[t] = c;
    }
    __syncthreads();
    for (int off = 1; off < 128; off <<= 1) {
        int u = (t >= off && t < 128) ? stmp[t - off] : 0;
        __syncthreads();
        if (t < 128) stmp[t] += u;
        __syncthreads();
    }
    if (t < 128) {
        const int ls = base + stmp[t] - c;  // exclusive, within bucket window
        lcur[t] = ls;
        const int node = b * 128 + t;
        if (node < N_NODES) {
            row_start[node] = ls;
            cnt[node] = c;
            const float di = rsqrtf((float)c + 1.0f);
            dinv[node] = di;
            wsd[node] = di * wsc[node];  // fused dequant+norm weight for gather
        }
    }
    __syncthreads();

    for (int i = t; i < n; i += 256) {
        const unsigned int p = pbuf[base + i];
        const int pos = atomicAdd(&lcur[p >> 16], 1);
        esrc[pos] = (int)(p & 0xFFFFu);
    }
}

// ---------------------------------------------------------------------------
// Fused gather + GEMM. Block = 64 rows, 512 threads = 8 waves.
// Phase 1: round-6's verified strided-slot pattern, widened to 8 slots:
//   lane = (slot s=lane>>3, chunk c=lane&7). Slot s walks edges beg+s, +8, ...
//   (2 in flight); the 8 lanes of a slot load the SAME esrc/wsd dword
//   (replicated-uniform) and each loads 16 B of the 128 B int8 row -> 8
//   row-requests per edge instead of round 6's 16 (the gather-wall resource).
//   acc[16] f32/lane; 3-level shfl_xor(8/16/32) reduce; lanes s==0 write the
//   bf16 XOR-swizzled LDS row (physical layout identical to round 6).
// Phase 2: wave w=(wr,wc) computes rows wr*16..+15, cols wc*64..+63 of
//   [64x256] @ Wab[256x128]: k 0..127 from LDS (g), k 128..255 from xb.
__global__ __launch_bounds__(512) void k_gmm(const unsigned short* __restrict__ xb,
                                             const char* __restrict__ qx,
                                             const int* __restrict__ row_start,
                                             const int* __restrict__ cnt,
                                             const float* __restrict__ dinv,
                                             const float* __restrict__ wsd,
                                             const int* __restrict__ esrc,
                                             const unsigned short* __restrict__ Wp,
                                             const float* __restrict__ bv,
                                             float* __restrict__ out) {
    __shared__ unsigned short sg[64 * 128];  // 16 KB, rows XOR-swizzled
    const int tid = threadIdx.x;
    const int wave = tid >> 6;  // 0..7
    const int lane = tid & 63;
    const int c = lane & 7;   // element chunk: elements 16c..16c+15
    const int s = lane >> 3;  // edge slot 0..7
    const int row0 = blockIdx.x * 64;

#pragma unroll
    for (int m = 0; m < 8; ++m) {
        const int node = row0 + wave * 8 + m;
        const bool valid = node < N_NODES;
        const int beg = valid ? row_start[node] : 0;
        const int end = beg + (valid ? cnt[node] : 0);
        float acc[16];
#pragma unroll
        for (int j = 0; j < 16; ++j) acc[j] = 0.0f;

        int i = beg + s;
        for (; i + 8 < end; i += 16) {  // two edges in flight per slot
            const int a0 = esrc[i];
            const int a1 = esrc[i + 8];
            const float w0 = wsd[a0];
            const float w1 = wsd[a1];
            const uint4 q0 = *(const uint4*)(qx + (long)a0 * 128 + c * 16);
            const uint4 q1 = *(const uint4*)(qx + (long)a1 * 128 + c * 16);
            GACC(q0, w0);
            GACC(q1, w1);
        }
        for (; i < end; i += 8) {  // tail
            const int a0 = esrc[i];
            const float w0 = wsd[a0];
            const uint4 q0 = *(const uint4*)(qx + (long)a0 * 128 + c * 16);
            GACC(q0, w0);
        }

        // reduce across the 8 slots (lane bits 3,4,5)
#pragma unroll
        for (int j = 0; j < 16; ++j) {
            acc[j] += __shfl_xor(acc[j], 8);
            acc[j] += __shfl_xor(acc[j], 16);
            acc[j] += __shfl_xor(acc[j], 32);
        }

        if (s == 0) {  // lanes 0..7: chunk c holds elements 16c..16c+15
            const int r = wave * 8 + m;  // LDS row
            alignas(16) unsigned short o[16];
#pragma unroll
            for (int j = 0; j < 16; ++j) o[j] = 0;
            if (valid) {
                const float di = dinv[node];
                const short8 xs0 = *(const short8*)(xb + (long)node * 128 + c * 16);
                const short8 xs1 = *(const short8*)(xb + (long)node * 128 + c * 16 + 8);
#pragma unroll
                for (int j = 0; j < 8; ++j) {
                    o[j] = f2bf(di * (acc[j] + di * bf2f((unsigned short)xs0[j])));
                    o[8 + j] =
                        f2bf(di * (acc[8 + j] + di * bf2f((unsigned short)xs1[j])));
                }
            }
            // logical byte offsets c*32 (elements 16c..) and c*32+16 (16c+8..),
            // physically identical placement to round 6's c'*16 writes
            const int b0 = (c * 32) ^ ((r & 7) << 4);
            const int b1 = (c * 32 + 16) ^ ((r & 7) << 4);
            *(uint4*)((char*)sg + r * 256 + b0) = *(const uint4*)&o[0];
            *(uint4*)((char*)sg + r * 256 + b1) = *(const uint4*)&o[8];
        }
    }
    __syncthreads();

    // ---- GEMM phase: wave (wr,wc) -> rows wr*16..+15, cols wc*64..+63 ----
    const int lr = lane & 15;
    const int quad = lane >> 4;
    const int wr = wave & 3;
    const int wc = wave >> 2;
    const int rloc = wr * 16 + lr;  // LDS row this lane reads
    int ar = row0 + rloc;
    if (ar >= N_NODES) ar = N_NODES - 1;  // clamp loads; stores are guarded
    const unsigned short* aptr = xb + (long)ar * 128 + quad * 8;

    f32x4 acc2[4] = {};
#pragma unroll
    for (int s8 = 0; s8 < 8; ++s8) {
        short8 a;
        if (s8 < 4) {
            const int colb = (s8 * 64 + quad * 16) ^ ((rloc & 7) << 4);
            a = *(const short8*)((const char*)sg + rloc * 256 + colb);
        } else {
            a = *(const short8*)(aptr + (s8 - 4) * 32);
        }
#pragma unroll
        for (int t2 = 0; t2 < 4; ++t2) {
            const short8 b =
                *(const short8*)(Wp + ((long)(s8 * 8 + wc * 4 + t2) * 64 + lane) * 8);
            acc2[t2] = __builtin_amdgcn_mfma_f32_16x16x32_bf16(a, b, acc2[t2], 0, 0, 0);
        }
    }

    const int rowbase = row0 + wr * 16;
#pragma unroll
    for (int t2 = 0; t2 < 4; ++t2) {
        const int col = wc * 64 + t2 * 16 + lr;
        const float bvv = bv[col];
#pragma unroll
        for (int r = 0; r < 4; ++r) {
            const int row = rowbase + quad * 4 + r;
            if (row < N_NODES) out[(long)row * D + col] = acc2[t2][r] + bvv;
        }
    }
}

// ---------------------------------------------------------------------------
extern "C" void kernel_launch(void* const* d_in, const int* in_sizes, int n_in,
                              void* d_out, int out_size, void* d_ws, size_t ws_size,
                              hipStream_t stream) {
    const float* x  = (const float*)d_in[0];
    const int*   ei = (const int*)d_in[1];  // [2, E] flat: row0=src, row1=dst
    const float* Wc = (const float*)d_in[2];
    const float* bc = (const float*)d_in[3];
    const float* W0 = (const float*)d_in[4];
    const float* Wt = (const float*)d_in[5];
    float* out = (float*)d_out;

    const int* src = ei;
    const int* dst = ei + N_EDGES;

    // workspace layout:
    //   xb bf16 [N*128] | qx i8 [N*128] | row_start [N] | cnt [N] | dinv [N] |
    //   wsc [N] | wsd [N] | esrc [NB*CAPB] | pbuf [NB*CAPB] | bv f32 [D] |
    //   Wp bf16 [256*128] | gcur [NB]
    unsigned short* xb = (unsigned short*)d_ws;
    char* qx          = (char*)(xb + (size_t)N_NODES * 128);
    int*   row_start  = (int*)(qx + (size_t)N_NODES * 128);
    int*   cnt        = row_start + N_NODES;
    float* dinv       = (float*)(cnt + N_NODES);
    float* wsc        = dinv + N_NODES;
    float* wsd        = wsc + N_NODES;
    int*   esrc       = (int*)(wsd + N_NODES);
    unsigned int* pbuf = (unsigned int*)(esrc + (size_t)NB * CAPB);
    float* bv         = (float*)(pbuf + (size_t)NB * CAPB);
    unsigned short* Wp = (unsigned short*)(bv + D);
    int*   gcur       = (int*)(Wp + 256 * D);

    k_init<<<1, 512, 0, stream>>>(gcur);
    k_a<<<KA_BLOCKS, 256, 0, stream>>>(src, dst, gcur, pbuf, Wc, W0, Wt, bc, x,
                                       Wp, bv, xb, qx, wsc);
    k_part2<<<NB, 256, 0, stream>>>(pbuf, gcur, wsc, row_start, cnt, dinv, wsd, esrc);
    k_gmm<<<(N_NODES + 63) / 64, 512, 0, stream>>>(xb, qx, row_start, cnt, dinv, wsd,
                                                   esrc, Wp, bv, out);
}